// Round 3
// baseline (1280.248 us; speedup 1.0000x reference)
//
#include <hip/hip_runtime.h>
#include <hip/hip_bf16.h>

#define N_TOK   8192
#define DIM     1024
#define HID     2048
#define NEXP    8
#define NSH     2
#define NSLOT   32768       // 2*N shared slots + 2*N routed slots
#define NPAD    256
#define MAXT    136

typedef unsigned int   u32;
typedef unsigned short u16;
typedef float  f32x4  __attribute__((ext_vector_type(4)));
typedef short  bf16x8 __attribute__((ext_vector_type(8)));

// ---------- workspace layout (bytes) ----------
#define OFF_CTRL  0u            // int counts[8], cursors[8..15], off_e[16..23], ntiles @24
#define OFF_DESC  256u          // int4 desc[MAXT]
#define OFF_TOK   4096u         // int   tok[NSLOT+NPAD]
#define OFF_WSC   136192u       // float wsc[NSLOT+NPAD]
#define OFF_TOPI  268288u       // int2  topi[N_TOK]
#define OFF_PROB  333824u       // float2 probs[N_TOK]
#define OFF_XB    399360u       // u16 x_bf16[N*D]
#define OFF_W1T   17176576u     // u16 w1t[E][H][D]
#define OFF_W2T   50731008u     // u16 w2t[E][D][H]
#define OFF_SW1T  84285440u     // u16 sw1t[S][H][D]
#define OFF_SW2T  92674048u     // u16 sw2t[S][D][H]
#define OFF_H     101062656u    // u16 h[NSLOT][H]   (no pad; gemm2 clamps)

__device__ __forceinline__ u16 f2bf(float f) {
  union { float f; u32 u; } v; v.f = f;
  u32 r = v.u + 0x7FFFu + ((v.u >> 16) & 1u);
  return (u16)(r >> 16);
}

// tanh-form gelu: x - x/(1+exp2(2.30211831*x + 0.10294494*x^3)); |err| vs erf-gelu ~3e-4
__device__ __forceinline__ float gelu_fast(float x) {
  float x2 = x * x;
  float v  = x * fmaf(x2, 0.10294494f, 2.30211831f);
  float z  = exp2f(v);
  float r  = __builtin_amdgcn_rcpf(1.0f + z);
  return x - x * r;
}

__device__ __forceinline__ void gll16(const void* g, void* l) {
  __builtin_amdgcn_global_load_lds((const __attribute__((address_space(1))) u32*)g,
                                   (__attribute__((address_space(3))) u32*)l, 16, 0, 0);
}

// ---------- fp32 [B][R][C] -> bf16 [B][C][R] ----------
__global__ void transpose_cvt_kernel(const float* __restrict__ in, u16* __restrict__ out,
                                     int R, int C) {
  __shared__ float t[32][33];
  int b = blockIdx.z;
  const float* ip = in + (size_t)b * R * C;
  u16* op = out + (size_t)b * R * C;
  int c0 = blockIdx.x * 32, r0 = blockIdx.y * 32;
  int tx = threadIdx.x, ty = threadIdx.y;  // block (32,8)
#pragma unroll
  for (int i = 0; i < 4; i++) {
    int r = ty + i * 8;
    t[r][tx] = ip[(size_t)(r0 + r) * C + c0 + tx];
  }
  __syncthreads();
#pragma unroll
  for (int i = 0; i < 4; i++) {
    int c = ty + i * 8;
    op[(size_t)(c0 + c) * R + r0 + tx] = f2bf(t[tx][c]);
  }
}

// ---------- router (+fused x->bf16): fp32 gates, top-2 softmax, counts ----------
__global__ __launch_bounds__(256) void router_kernel(
    const float* __restrict__ x, const float* __restrict__ rw, const float* __restrict__ rb,
    int* __restrict__ ctrl, int2* __restrict__ topi, float2* __restrict__ probs,
    u16* __restrict__ xb) {
  int n = blockIdx.x * 4 + (threadIdx.x >> 6);
  int lane = threadIdx.x & 63;
  float acc[NEXP];
#pragma unroll
  for (int e = 0; e < NEXP; e++) acc[e] = 0.f;
  const float* xrow = x + (size_t)n * DIM;
  u16* xbrow = xb + (size_t)n * DIM;
#pragma unroll 4
  for (int i = 0; i < DIM / 64; i++) {
    int d = i * 64 + lane;
    float xv = xrow[d];
    xbrow[d] = f2bf(xv);
    const float4* r4 = (const float4*)(rw + (size_t)d * NEXP);
    float4 a = r4[0], b = r4[1];
    acc[0] += xv * a.x; acc[1] += xv * a.y; acc[2] += xv * a.z; acc[3] += xv * a.w;
    acc[4] += xv * b.x; acc[5] += xv * b.y; acc[6] += xv * b.z; acc[7] += xv * b.w;
  }
#pragma unroll
  for (int e = 0; e < NEXP; e++) {
    float v = acc[e];
    for (int off = 32; off > 0; off >>= 1) v += __shfl_down(v, off);
    acc[e] = v;
  }
  if (lane == 0) {
    float g[NEXP];
#pragma unroll
    for (int e = 0; e < NEXP; e++) g[e] = acc[e] + rb[e];
    int i0 = 0; float v0 = g[0];
#pragma unroll
    for (int e = 1; e < NEXP; e++) if (g[e] > v0) { v0 = g[e]; i0 = e; }
    int i1 = -1; float v1 = -1e30f;
#pragma unroll
    for (int e = 0; e < NEXP; e++) if (e != i0 && g[e] > v1) { v1 = g[e]; i1 = e; }
    float e1 = expf(v1 - v0);
    float p0 = 1.f / (1.f + e1);
    float p1 = 1.f - p0;
    topi[n]  = make_int2(i0, i1);
    probs[n] = make_float2(p0, p1);
    atomicAdd(&ctrl[i0], 1);
    atomicAdd(&ctrl[i1], 1);
  }
}

// ---------- plan: offsets + 256-row tile descriptors ----------
__global__ void plan_kernel(int* __restrict__ ctrl, int4* __restrict__ desc) {
  int nt = 0;
  for (int s = 0; s < NSH; s++)
    for (int i = 0; i < N_TOK / 256; i++)
      desc[nt++] = make_int4(s, s * N_TOK + i * 256, 256, 0);
  int off = 0;
  for (int e = 0; e < NEXP; e++) {
    int cnt = ctrl[e];
    ctrl[16 + e] = off;
    int base = 2 * N_TOK + off;
    for (int i = 0; i * 256 < cnt; i++) {
      int rows = cnt - i * 256; if (rows > 256) rows = 256;
      desc[nt++] = make_int4(2 + e, base + i * 256, rows, 0);
    }
    off += cnt;
  }
  ctrl[24] = nt;
}

// ---------- assign: fill token/scale slot arrays ----------
__global__ void assign_kernel(const int2* __restrict__ topi, const float2* __restrict__ probs,
                              int* __restrict__ ctrl, int* __restrict__ tok,
                              float* __restrict__ wsc) {
  int n = blockIdx.x * blockDim.x + threadIdx.x;
  if (n >= N_TOK) return;
  tok[n] = n;           wsc[n] = 0.5f;
  tok[N_TOK + n] = n;   wsc[N_TOK + n] = 0.5f;
  int2 ti = topi[n]; float2 p = probs[n];
  int pos  = atomicAdd(&ctrl[8 + ti.x], 1);
  int slot = 2 * N_TOK + ctrl[16 + ti.x] + pos;
  tok[slot] = n; wsc[slot] = p.x;
  pos  = atomicAdd(&ctrl[8 + ti.y], 1);
  slot = 2 * N_TOK + ctrl[16 + ti.y] + pos;
  tok[slot] = n; wsc[slot] = p.y;
  if (n < NPAD) { tok[NSLOT + n] = 0; wsc[NSLOT + n] = 0.f; }
}

// ================= 256x256 BK=32 double-buffered grouped GEMMs =================
// 8 waves: wm = wave>>2 (2 row-halves of 128), wn = wave&3 (4 col-blocks of 64).
// Per-wave output 128x64: acc[8][4] f32x4. LDS 64KB (2 bufs x (A 16KB + B 16KB)).

#define G_STAGE(buf, k0)                       \
  {                                            \
    gll16(sA0 + (k0), &As[buf][idx0 * 8]);     \
    gll16(sA1 + (k0), &As[buf][idx1 * 8]);     \
    gll16(sB0 + (k0), &Bs[buf][idx0 * 8]);     \
    gll16(sB1 + (k0), &Bs[buf][idx1 * 8]);     \
  }

#define G_COMPUTE(buf)                                                              \
  {                                                                                 \
    bf16x8 a[8], b[4];                                                              \
    _Pragma("unroll") for (int m = 0; m < 8; m++)                                   \
      a[m] = *(const bf16x8*)&As[buf][(wm * 128 + m * 16 + (lane & 15)) * 32 +      \
                                      (lane >> 4) * 8];                             \
    _Pragma("unroll") for (int n = 0; n < 4; n++)                                   \
      b[n] = *(const bf16x8*)&Bs[buf][(wn * 64 + n * 16 + (lane & 15)) * 32 +       \
                                      (lane >> 4) * 8];                             \
    _Pragma("unroll") for (int m = 0; m < 8; m++)                                   \
      _Pragma("unroll") for (int n = 0; n < 4; n++)                                 \
        acc[m][n] = __builtin_amdgcn_mfma_f32_16x16x32_bf16(a[m], b[n], acc[m][n],  \
                                                            0, 0, 0);               \
  }

// ---------- GEMM1: h = gelu(gather(x) @ w1[g]^T + b1[g]) -> bf16 ----------
__global__ __launch_bounds__(512, 2) void gemm1_kernel(
    const u16* __restrict__ xb, const u16* __restrict__ w1t, const u16* __restrict__ sw1t,
    const float* __restrict__ b1, const float* __restrict__ sb1,
    const int* __restrict__ ctrl, const int4* __restrict__ desc,
    const int* __restrict__ tok, u16* __restrict__ hbuf) {
  int t = blockIdx.y;
  if (t >= ctrl[24]) return;
  int4 d = desc[t];
  int g = d.x, slot0 = d.y, rows = d.z;
  int n0 = blockIdx.x * 256;
  const u16* Bb = (g < NSH) ? (sw1t + (size_t)g * HID * DIM)
                            : (w1t + (size_t)(g - NSH) * HID * DIM);
  const float* bias = (g < NSH) ? (sb1 + (size_t)g * HID) : (b1 + (size_t)(g - NSH) * HID);

  __shared__ u16 As[2][256 * 32];
  __shared__ u16 Bs[2][256 * 32];
  int tid = threadIdx.x;
  int wave = tid >> 6, lane = tid & 63;
  int wm = wave >> 2, wn = wave & 3;

  // staging: 1024 16B-chunks each for A,B; chunk idx -> (row=idx>>2, kk=(idx&3)*8)
  int idx0 = wave * 128 + lane, idx1 = idx0 + 64;
  int row0 = idx0 >> 2, row1 = idx1 >> 2;
  int kk0 = (idx0 & 3) * 8, kk1 = (idx1 & 3) * 8;
  const u16* sA0 = xb + (size_t)tok[slot0 + row0] * DIM + kk0;
  const u16* sA1 = xb + (size_t)tok[slot0 + row1] * DIM + kk1;
  const u16* sB0 = Bb + (size_t)(n0 + row0) * DIM + kk0;
  const u16* sB1 = Bb + (size_t)(n0 + row1) * DIM + kk1;

  f32x4 acc[8][4];
#pragma unroll
  for (int m = 0; m < 8; m++)
#pragma unroll
    for (int n = 0; n < 4; n++) acc[m][n] = (f32x4){0.f, 0.f, 0.f, 0.f};

  G_STAGE(0, 0);
  __syncthreads();
  int cur = 0;
  for (int tt = 0; tt < DIM / 32; ++tt) {
    if (tt + 1 < DIM / 32) G_STAGE(cur ^ 1, (tt + 1) * 32);
    G_COMPUTE(cur);
    __syncthreads();
    cur ^= 1;
  }

  int lc = lane & 15, lr4 = (lane >> 4) * 4;
#pragma unroll
  for (int n = 0; n < 4; n++) {
    int col = n0 + wn * 64 + n * 16 + lc;
    float bc = bias[col];
#pragma unroll
    for (int m = 0; m < 8; m++) {
      f32x4 v = acc[m][n];
#pragma unroll
      for (int r = 0; r < 4; r++) {
        int lrow = wm * 128 + m * 16 + lr4 + r;
        if (lrow < rows)
          hbuf[(size_t)(slot0 + lrow) * HID + col] = f2bf(gelu_fast(v[r] + bc));
      }
    }
  }
}

// ---------- GEMM2: out[tok] += scale * (h @ w2[g]^T + b2[g]) ----------
__global__ __launch_bounds__(512, 2) void gemm2_kernel(
    const u16* __restrict__ hbuf, const u16* __restrict__ w2t, const u16* __restrict__ sw2t,
    const float* __restrict__ b2, const float* __restrict__ sb2,
    const int* __restrict__ ctrl, const int4* __restrict__ desc,
    const int* __restrict__ tok, const float* __restrict__ wsc, float* __restrict__ out) {
  int t = blockIdx.y;
  if (t >= ctrl[24]) return;
  int4 d = desc[t];
  int g = d.x, slot0 = d.y, rows = d.z;
  int n0 = blockIdx.x * 256;
  const u16* Bb = (g < NSH) ? (sw2t + (size_t)g * HID * DIM)
                            : (w2t + (size_t)(g - NSH) * HID * DIM);
  const float* bias = (g < NSH) ? (sb2 + (size_t)g * DIM) : (b2 + (size_t)(g - NSH) * DIM);

  __shared__ u16 As[2][256 * 32];
  __shared__ u16 Bs[2][256 * 32];
  int tid = threadIdx.x;
  int wave = tid >> 6, lane = tid & 63;
  int wm = wave >> 2, wn = wave & 3;

  int idx0 = wave * 128 + lane, idx1 = idx0 + 64;
  int row0 = idx0 >> 2, row1 = idx1 >> 2;
  int kk0 = (idx0 & 3) * 8, kk1 = (idx1 & 3) * 8;
  int ra0 = (row0 < rows) ? row0 : 0;  // clamp: hbuf has no pad rows
  int ra1 = (row1 < rows) ? row1 : 0;
  const u16* sA0 = hbuf + (size_t)(slot0 + ra0) * HID + kk0;
  const u16* sA1 = hbuf + (size_t)(slot0 + ra1) * HID + kk1;
  const u16* sB0 = Bb + (size_t)(n0 + row0) * HID + kk0;
  const u16* sB1 = Bb + (size_t)(n0 + row1) * HID + kk1;

  f32x4 acc[8][4];
#pragma unroll
  for (int m = 0; m < 8; m++)
#pragma unroll
    for (int n = 0; n < 4; n++) acc[m][n] = (f32x4){0.f, 0.f, 0.f, 0.f};

  G_STAGE(0, 0);
  __syncthreads();
  int cur = 0;
  for (int tt = 0; tt < HID / 32; ++tt) {
    if (tt + 1 < HID / 32) G_STAGE(cur ^ 1, (tt + 1) * 32);
    G_COMPUTE(cur);
    __syncthreads();
    cur ^= 1;
  }

  int lc = lane & 15, lr4 = (lane >> 4) * 4;
#pragma unroll
  for (int n = 0; n < 4; n++) {
    int col = n0 + wn * 64 + n * 16 + lc;
    float bc = bias[col];
#pragma unroll
    for (int m = 0; m < 8; m++) {
      f32x4 v = acc[m][n];
#pragma unroll
      for (int r = 0; r < 4; r++) {
        int lrow = wm * 128 + m * 16 + lr4 + r;
        if (lrow < rows) {
          int slot = slot0 + lrow;
          atomicAdd(&out[(size_t)tok[slot] * DIM + col], wsc[slot] * (v[r] + bc));
        }
      }
    }
  }
}

extern "C" void kernel_launch(void* const* d_in, const int* in_sizes, int n_in,
                              void* d_out, int out_size, void* d_ws, size_t ws_size,
                              hipStream_t stream) {
  const float* x   = (const float*)d_in[0];
  const float* rw  = (const float*)d_in[1];
  const float* rb  = (const float*)d_in[2];
  const float* w1  = (const float*)d_in[3];
  const float* b1  = (const float*)d_in[4];
  const float* w2  = (const float*)d_in[5];
  const float* b2  = (const float*)d_in[6];
  const float* sw1 = (const float*)d_in[7];
  const float* sb1 = (const float*)d_in[8];
  const float* sw2 = (const float*)d_in[9];
  const float* sb2 = (const float*)d_in[10];
  float* out = (float*)d_out;

  char* w = (char*)d_ws;
  int*    ctrl  = (int*)(w + OFF_CTRL);
  int4*   desc  = (int4*)(w + OFF_DESC);
  int*    tok   = (int*)(w + OFF_TOK);
  float*  wsc   = (float*)(w + OFF_WSC);
  int2*   topi  = (int2*)(w + OFF_TOPI);
  float2* probs = (float2*)(w + OFF_PROB);
  u16*    xb    = (u16*)(w + OFF_XB);
  u16*    w1t   = (u16*)(w + OFF_W1T);
  u16*    w2t   = (u16*)(w + OFF_W2T);
  u16*    sw1t  = (u16*)(w + OFF_SW1T);
  u16*    sw2t  = (u16*)(w + OFF_SW2T);
  u16*    hbuf  = (u16*)(w + OFF_H);

  hipMemsetAsync(d_out, 0, (size_t)out_size * sizeof(float), stream);
  hipMemsetAsync(d_ws, 0, 256, stream);

  // weight transposes (fp32 -> bf16, [R][C] -> [C][R])
  transpose_cvt_kernel<<<dim3(HID / 32, DIM / 32, NEXP), dim3(32, 8), 0, stream>>>(w1, w1t, DIM, HID);
  transpose_cvt_kernel<<<dim3(DIM / 32, HID / 32, NEXP), dim3(32, 8), 0, stream>>>(w2, w2t, HID, DIM);
  transpose_cvt_kernel<<<dim3(HID / 32, DIM / 32, NSH), dim3(32, 8), 0, stream>>>(sw1, sw1t, DIM, HID);
  transpose_cvt_kernel<<<dim3(DIM / 32, HID / 32, NSH), dim3(32, 8), 0, stream>>>(sw2, sw2t, HID, DIM);

  // routing (+x cast)
  router_kernel<<<N_TOK / 4, 256, 0, stream>>>(x, rw, rb, ctrl, topi, probs, xb);
  plan_kernel<<<1, 1, 0, stream>>>(ctrl, desc);
  assign_kernel<<<N_TOK / 256, 256, 0, stream>>>(topi, probs, ctrl, tok, wsc);

  // grouped GEMMs (256x256 tiles)
  gemm1_kernel<<<dim3(HID / 256, MAXT), 512, 0, stream>>>(xb, w1t, sw1t, b1, sb1,
                                                          ctrl, desc, tok, hbuf);
  gemm2_kernel<<<dim3(DIM / 256, MAXT), 512, 0, stream>>>(hbuf, w2t, sw2t, b2, sb2,
                                                          ctrl, desc, tok, wsc, out);
}

// Round 4
// 1261.127 us; speedup vs baseline: 1.0152x; 1.0152x over previous
//
#include <hip/hip_runtime.h>
#include <hip/hip_bf16.h>

#define N_TOK   8192
#define DIM     1024
#define HID     2048
#define NEXP    8
#define NSH     2
#define NSLOT   32768       // 2*N shared slots + 2*N routed slots
#define NPAD    256
#define MAXT    136

typedef unsigned int   u32;
typedef unsigned short u16;
typedef float  f32x4  __attribute__((ext_vector_type(4)));
typedef short  bf16x8 __attribute__((ext_vector_type(8)));

// ---------- workspace layout (bytes) ----------
#define OFF_CTRL  0u            // int counts[8], cursors[8..15], off_e[16..23], ntiles @24
#define OFF_DESC  256u          // int4 desc[MAXT]
#define OFF_TOK   4096u         // int   tok[NSLOT+NPAD]
#define OFF_WSC   136192u       // float wsc[NSLOT+NPAD]
#define OFF_TOPI  268288u       // int2  topi[N_TOK]
#define OFF_PROB  333824u       // float2 probs[N_TOK]
#define OFF_XB    399360u       // u16 x_bf16[N*D]
#define OFF_W1T   17176576u     // u16 w1t[E][H][D]
#define OFF_W2T   50731008u     // u16 w2t[E][D][H]
#define OFF_SW1T  84285440u     // u16 sw1t[S][H][D]
#define OFF_SW2T  92674048u     // u16 sw2t[S][D][H]
#define OFF_H     101062656u    // u16 h[NSLOT][H]   (no pad; gemm2 clamps)

__device__ __forceinline__ u16 f2bf(float f) {
  union { float f; u32 u; } v; v.f = f;
  u32 r = v.u + 0x7FFFu + ((v.u >> 16) & 1u);
  return (u16)(r >> 16);
}

// tanh-form gelu: |err| vs erf-gelu ~3e-4 (far under bf16 noise)
__device__ __forceinline__ float gelu_fast(float x) {
  float x2 = x * x;
  float v  = x * fmaf(x2, 0.10294494f, 2.30211831f);
  float z  = exp2f(v);
  float r  = __builtin_amdgcn_rcpf(1.0f + z);
  return x - x * r;
}

__device__ __forceinline__ void gll16(const void* g, void* l) {
  __builtin_amdgcn_global_load_lds((const __attribute__((address_space(1))) u32*)g,
                                   (__attribute__((address_space(3))) u32*)l, 16, 0, 0);
}

// ---------- fp32 [B][R][C] -> bf16 [B][C][R] ----------
__global__ void transpose_cvt_kernel(const float* __restrict__ in, u16* __restrict__ out,
                                     int R, int C) {
  __shared__ float t[32][33];
  int b = blockIdx.z;
  const float* ip = in + (size_t)b * R * C;
  u16* op = out + (size_t)b * R * C;
  int c0 = blockIdx.x * 32, r0 = blockIdx.y * 32;
  int tx = threadIdx.x, ty = threadIdx.y;  // block (32,8)
#pragma unroll
  for (int i = 0; i < 4; i++) {
    int r = ty + i * 8;
    t[r][tx] = ip[(size_t)(r0 + r) * C + c0 + tx];
  }
  __syncthreads();
#pragma unroll
  for (int i = 0; i < 4; i++) {
    int c = ty + i * 8;
    op[(size_t)(c0 + c) * R + r0 + tx] = f2bf(t[tx][c]);
  }
}

// ---------- router (+fused x->bf16): fp32 gates, top-2 softmax, counts ----------
__global__ __launch_bounds__(256) void router_kernel(
    const float* __restrict__ x, const float* __restrict__ rw, const float* __restrict__ rb,
    int* __restrict__ ctrl, int2* __restrict__ topi, float2* __restrict__ probs,
    u16* __restrict__ xb) {
  int n = blockIdx.x * 4 + (threadIdx.x >> 6);
  int lane = threadIdx.x & 63;
  float acc[NEXP];
#pragma unroll
  for (int e = 0; e < NEXP; e++) acc[e] = 0.f;
  const float* xrow = x + (size_t)n * DIM;
  u16* xbrow = xb + (size_t)n * DIM;
#pragma unroll 4
  for (int i = 0; i < DIM / 64; i++) {
    int d = i * 64 + lane;
    float xv = xrow[d];
    xbrow[d] = f2bf(xv);
    const float4* r4 = (const float4*)(rw + (size_t)d * NEXP);
    float4 a = r4[0], b = r4[1];
    acc[0] += xv * a.x; acc[1] += xv * a.y; acc[2] += xv * a.z; acc[3] += xv * a.w;
    acc[4] += xv * b.x; acc[5] += xv * b.y; acc[6] += xv * b.z; acc[7] += xv * b.w;
  }
#pragma unroll
  for (int e = 0; e < NEXP; e++) {
    float v = acc[e];
    for (int off = 32; off > 0; off >>= 1) v += __shfl_down(v, off);
    acc[e] = v;
  }
  if (lane == 0) {
    float g[NEXP];
#pragma unroll
    for (int e = 0; e < NEXP; e++) g[e] = acc[e] + rb[e];
    int i0 = 0; float v0 = g[0];
#pragma unroll
    for (int e = 1; e < NEXP; e++) if (g[e] > v0) { v0 = g[e]; i0 = e; }
    int i1 = -1; float v1 = -1e30f;
#pragma unroll
    for (int e = 0; e < NEXP; e++) if (e != i0 && g[e] > v1) { v1 = g[e]; i1 = e; }
    float e1 = expf(v1 - v0);
    float p0 = 1.f / (1.f + e1);
    float p1 = 1.f - p0;
    topi[n]  = make_int2(i0, i1);
    probs[n] = make_float2(p0, p1);
    atomicAdd(&ctrl[i0], 1);
    atomicAdd(&ctrl[i1], 1);
  }
}

// ---------- plan: offsets + 256-row tile descriptors ----------
__global__ void plan_kernel(int* __restrict__ ctrl, int4* __restrict__ desc) {
  int nt = 0;
  for (int s = 0; s < NSH; s++)
    for (int i = 0; i < N_TOK / 256; i++)
      desc[nt++] = make_int4(s, s * N_TOK + i * 256, 256, 0);
  int off = 0;
  for (int e = 0; e < NEXP; e++) {
    int cnt = ctrl[e];
    ctrl[16 + e] = off;
    int base = 2 * N_TOK + off;
    for (int i = 0; i * 256 < cnt; i++) {
      int rows = cnt - i * 256; if (rows > 256) rows = 256;
      desc[nt++] = make_int4(2 + e, base + i * 256, rows, 0);
    }
    off += cnt;
  }
  ctrl[24] = nt;
}

// ---------- assign: fill token/scale slot arrays ----------
__global__ void assign_kernel(const int2* __restrict__ topi, const float2* __restrict__ probs,
                              int* __restrict__ ctrl, int* __restrict__ tok,
                              float* __restrict__ wsc) {
  int n = blockIdx.x * blockDim.x + threadIdx.x;
  if (n >= N_TOK) return;
  tok[n] = n;           wsc[n] = 0.5f;
  tok[N_TOK + n] = n;   wsc[N_TOK + n] = 0.5f;
  int2 ti = topi[n]; float2 p = probs[n];
  int pos  = atomicAdd(&ctrl[8 + ti.x], 1);
  int slot = 2 * N_TOK + ctrl[16 + ti.x] + pos;
  tok[slot] = n; wsc[slot] = p.x;
  pos  = atomicAdd(&ctrl[8 + ti.y], 1);
  slot = 2 * N_TOK + ctrl[16 + ti.y] + pos;
  tok[slot] = n; wsc[slot] = p.y;
  if (n < NPAD) { tok[NSLOT + n] = 0; wsc[NSLOT + n] = 0.f; }
}

// ============ 256x256 BK=32, counted-vmcnt pipelined grouped GEMMs ============
// 8 waves: wm = wave>>2 (2 row-halves of 128), wn = wave&3 (4 col-blocks of 64).
// LDS linear [256][32] bf16 per buffer; content column-chunk-swizzled:
//   LDS chunk (row, q) holds global (row, q ^ ((row>>1)&3))  [16B chunks]
// so fragment reads (lanes 0-15 = rows r..r+15, same k-chunk) spread banks.
// Staging pre-applies the inverse permutation on the GLOBAL source address
// (global_load_lds dest must stay linear: wave-uniform base + lane*16).

#define G_STAGE(buf, k0)                       \
  {                                            \
    gll16(sA0 + (k0), &As[buf][idx0 * 8]);     \
    gll16(sA1 + (k0), &As[buf][idx1 * 8]);     \
    gll16(sB0 + (k0), &Bs[buf][idx0 * 8]);     \
    gll16(sB1 + (k0), &Bs[buf][idx1 * 8]);     \
  }

#define G_COMPUTE(buf)                                                              \
  {                                                                                 \
    bf16x8 a[8], b[4];                                                              \
    _Pragma("unroll") for (int m = 0; m < 8; m++)                                   \
      a[m] = *(const bf16x8*)&As[buf][(wm * 128 + m * 16 + (lane & 15)) * 32 +      \
                                      scc * 8];                                     \
    _Pragma("unroll") for (int n = 0; n < 4; n++)                                   \
      b[n] = *(const bf16x8*)&Bs[buf][(wn * 64 + n * 16 + (lane & 15)) * 32 +       \
                                      scc * 8];                                     \
    _Pragma("unroll") for (int m = 0; m < 8; m++)                                   \
      _Pragma("unroll") for (int n = 0; n < 4; n++)                                 \
        acc[m][n] = __builtin_amdgcn_mfma_f32_16x16x32_bf16(a[m], b[n], acc[m][n],  \
                                                            0, 0, 0);               \
  }

#define WAIT4   { asm volatile("s_waitcnt vmcnt(4)" ::: "memory"); \
                  __builtin_amdgcn_sched_barrier(0); }
#define WAIT0   { asm volatile("s_waitcnt vmcnt(0)" ::: "memory"); \
                  __builtin_amdgcn_sched_barrier(0); }
#define BAR     { __builtin_amdgcn_s_barrier(); __builtin_amdgcn_sched_barrier(0); }

// ---------- GEMM1: h = gelu(gather(x) @ w1[g]^T + b1[g]) -> bf16 ----------
__global__ __launch_bounds__(512) void gemm1_kernel(
    const u16* __restrict__ xb, const u16* __restrict__ w1t, const u16* __restrict__ sw1t,
    const float* __restrict__ b1, const float* __restrict__ sb1,
    const int* __restrict__ ctrl, const int4* __restrict__ desc,
    const int* __restrict__ tok, u16* __restrict__ hbuf) {
  // T1 chunked XCD swizzle (nwg = 8*136 = 1088, %8==0 -> bijective)
  int flat = blockIdx.y * 8 + blockIdx.x;
  int swz  = (flat & 7) * (MAXT * 8 / 8) + (flat >> 3);
  int bx = swz & 7, t = swz >> 3;
  if (t >= ctrl[24]) return;
  int4 d = desc[t];
  int g = d.x, slot0 = d.y, rows = d.z;
  int n0 = bx * 256;
  const u16* Bb = (g < NSH) ? (sw1t + (size_t)g * HID * DIM)
                            : (w1t + (size_t)(g - NSH) * HID * DIM);
  const float* bias = (g < NSH) ? (sb1 + (size_t)g * HID) : (b1 + (size_t)(g - NSH) * HID);

  __shared__ u16 As[2][256 * 32];
  __shared__ u16 Bs[2][256 * 32];
  int tid = threadIdx.x;
  int wave = tid >> 6, lane = tid & 63;
  int wm = wave >> 2, wn = wave & 3;
  int scc = (lane >> 4) ^ ((lane >> 1) & 3);   // swizzled read chunk (lane-const)

  // staging: 1024 16B-chunks each; chunk idx -> row=idx>>2, q=idx&3; src chunk = q^((row>>1)&3)
  int idx0 = wave * 128 + lane, idx1 = idx0 + 64;
  int row0 = idx0 >> 2, row1 = idx1 >> 2;
  int kk0 = (((idx0 & 3) ^ ((row0 >> 1) & 3)) * 8);
  int kk1 = (((idx1 & 3) ^ ((row1 >> 1) & 3)) * 8);
  const u16* sA0 = xb + (size_t)tok[slot0 + row0] * DIM + kk0;
  const u16* sA1 = xb + (size_t)tok[slot0 + row1] * DIM + kk1;
  const u16* sB0 = Bb + (size_t)(n0 + row0) * DIM + kk0;
  const u16* sB1 = Bb + (size_t)(n0 + row1) * DIM + kk1;

  f32x4 acc[8][4];
#pragma unroll
  for (int m = 0; m < 8; m++)
#pragma unroll
    for (int n = 0; n < 4; n++) acc[m][n] = (f32x4){0.f, 0.f, 0.f, 0.f};

  G_STAGE(0, 0);
  int cur = 0;
  for (int tt = 0; tt < DIM / 32 - 1; ++tt) {
    G_STAGE(cur ^ 1, (tt + 1) * 32);
    WAIT4; BAR;                 // tile tt staged (its loads issued one phase ago)
    G_COMPUTE(cur);
    BAR;                        // all reads of buf done before next overwrite
    cur ^= 1;
  }
  WAIT0; BAR;
  G_COMPUTE(cur);

  int lc = lane & 15, lr4 = (lane >> 4) * 4;
#pragma unroll
  for (int n = 0; n < 4; n++) {
    int col = n0 + wn * 64 + n * 16 + lc;
    float bc = bias[col];
#pragma unroll
    for (int m = 0; m < 8; m++) {
      f32x4 v = acc[m][n];
#pragma unroll
      for (int r = 0; r < 4; r++) {
        int lrow = wm * 128 + m * 16 + lr4 + r;
        if (lrow < rows)
          hbuf[(size_t)(slot0 + lrow) * HID + col] = f2bf(gelu_fast(v[r] + bc));
      }
    }
  }
}

// ---------- GEMM2: out[tok] += scale * (h @ w2[g]^T + b2[g]) ----------
__global__ __launch_bounds__(512) void gemm2_kernel(
    const u16* __restrict__ hbuf, const u16* __restrict__ w2t, const u16* __restrict__ sw2t,
    const float* __restrict__ b2, const float* __restrict__ sb2,
    const int* __restrict__ ctrl, const int4* __restrict__ desc,
    const int* __restrict__ tok, const float* __restrict__ wsc, float* __restrict__ out) {
  // T1 chunked XCD swizzle (nwg = 4*136 = 544, %8==0 -> bijective)
  int flat = blockIdx.y * 4 + blockIdx.x;
  int swz  = (flat & 7) * (MAXT * 4 / 8) + (flat >> 3);
  int bx = swz & 3, t = swz >> 2;
  if (t >= ctrl[24]) return;
  int4 d = desc[t];
  int g = d.x, slot0 = d.y, rows = d.z;
  int n0 = bx * 256;
  const u16* Bb = (g < NSH) ? (sw2t + (size_t)g * HID * DIM)
                            : (w2t + (size_t)(g - NSH) * HID * DIM);
  const float* bias = (g < NSH) ? (sb2 + (size_t)g * DIM) : (b2 + (size_t)(g - NSH) * DIM);

  __shared__ u16 As[2][256 * 32];
  __shared__ u16 Bs[2][256 * 32];
  int tid = threadIdx.x;
  int wave = tid >> 6, lane = tid & 63;
  int wm = wave >> 2, wn = wave & 3;
  int scc = (lane >> 4) ^ ((lane >> 1) & 3);

  int idx0 = wave * 128 + lane, idx1 = idx0 + 64;
  int row0 = idx0 >> 2, row1 = idx1 >> 2;
  int kk0 = (((idx0 & 3) ^ ((row0 >> 1) & 3)) * 8);
  int kk1 = (((idx1 & 3) ^ ((row1 >> 1) & 3)) * 8);
  int ra0 = (row0 < rows) ? row0 : 0;  // clamp: hbuf has no pad rows
  int ra1 = (row1 < rows) ? row1 : 0;
  const u16* sA0 = hbuf + (size_t)(slot0 + ra0) * HID + kk0;
  const u16* sA1 = hbuf + (size_t)(slot0 + ra1) * HID + kk1;
  const u16* sB0 = Bb + (size_t)(n0 + row0) * HID + kk0;
  const u16* sB1 = Bb + (size_t)(n0 + row1) * HID + kk1;

  f32x4 acc[8][4];
#pragma unroll
  for (int m = 0; m < 8; m++)
#pragma unroll
    for (int n = 0; n < 4; n++) acc[m][n] = (f32x4){0.f, 0.f, 0.f, 0.f};

  G_STAGE(0, 0);
  int cur = 0;
  for (int tt = 0; tt < HID / 32 - 1; ++tt) {
    G_STAGE(cur ^ 1, (tt + 1) * 32);
    WAIT4; BAR;
    G_COMPUTE(cur);
    BAR;
    cur ^= 1;
  }
  WAIT0; BAR;
  G_COMPUTE(cur);

  int lc = lane & 15, lr4 = (lane >> 4) * 4;
#pragma unroll
  for (int n = 0; n < 4; n++) {
    int col = n0 + wn * 64 + n * 16 + lc;
    float bc = bias[col];
#pragma unroll
    for (int m = 0; m < 8; m++) {
      f32x4 v = acc[m][n];
#pragma unroll
      for (int r = 0; r < 4; r++) {
        int lrow = wm * 128 + m * 16 + lr4 + r;
        if (lrow < rows) {
          int slot = slot0 + lrow;
          atomicAdd(&out[(size_t)tok[slot] * DIM + col], wsc[slot] * (v[r] + bc));
        }
      }
    }
  }
}

extern "C" void kernel_launch(void* const* d_in, const int* in_sizes, int n_in,
                              void* d_out, int out_size, void* d_ws, size_t ws_size,
                              hipStream_t stream) {
  const float* x   = (const float*)d_in[0];
  const float* rw  = (const float*)d_in[1];
  const float* rb  = (const float*)d_in[2];
  const float* w1  = (const float*)d_in[3];
  const float* b1  = (const float*)d_in[4];
  const float* w2  = (const float*)d_in[5];
  const float* b2  = (const float*)d_in[6];
  const float* sw1 = (const float*)d_in[7];
  const float* sb1 = (const float*)d_in[8];
  const float* sw2 = (const float*)d_in[9];
  const float* sb2 = (const float*)d_in[10];
  float* out = (float*)d_out;

  char* w = (char*)d_ws;
  int*    ctrl  = (int*)(w + OFF_CTRL);
  int4*   desc  = (int4*)(w + OFF_DESC);
  int*    tok   = (int*)(w + OFF_TOK);
  float*  wsc   = (float*)(w + OFF_WSC);
  int2*   topi  = (int2*)(w + OFF_TOPI);
  float2* probs = (float2*)(w + OFF_PROB);
  u16*    xb    = (u16*)(w + OFF_XB);
  u16*    w1t   = (u16*)(w + OFF_W1T);
  u16*    w2t   = (u16*)(w + OFF_W2T);
  u16*    sw1t  = (u16*)(w + OFF_SW1T);
  u16*    sw2t  = (u16*)(w + OFF_SW2T);
  u16*    hbuf  = (u16*)(w + OFF_H);

  hipMemsetAsync(d_out, 0, (size_t)out_size * sizeof(float), stream);
  hipMemsetAsync(d_ws, 0, 256, stream);

  // weight transposes (fp32 -> bf16, [R][C] -> [C][R])
  transpose_cvt_kernel<<<dim3(HID / 32, DIM / 32, NEXP), dim3(32, 8), 0, stream>>>(w1, w1t, DIM, HID);
  transpose_cvt_kernel<<<dim3(DIM / 32, HID / 32, NEXP), dim3(32, 8), 0, stream>>>(w2, w2t, HID, DIM);
  transpose_cvt_kernel<<<dim3(HID / 32, DIM / 32, NSH), dim3(32, 8), 0, stream>>>(sw1, sw1t, DIM, HID);
  transpose_cvt_kernel<<<dim3(DIM / 32, HID / 32, NSH), dim3(32, 8), 0, stream>>>(sw2, sw2t, HID, DIM);

  // routing (+x cast)
  router_kernel<<<N_TOK / 4, 256, 0, stream>>>(x, rw, rb, ctrl, topi, probs, xb);
  plan_kernel<<<1, 1, 0, stream>>>(ctrl, desc);
  assign_kernel<<<N_TOK / 256, 256, 0, stream>>>(topi, probs, ctrl, tok, wsc);

  // grouped GEMMs (256x256 tiles, counted-vmcnt pipeline)
  gemm1_kernel<<<dim3(HID / 256, MAXT), 512, 0, stream>>>(xb, w1t, sw1t, b1, sb1,
                                                          ctrl, desc, tok, hbuf);
  gemm2_kernel<<<dim3(DIM / 256, MAXT), 512, 0, stream>>>(hbuf, w2t, sw2t, b2, sb2,
                                                          ctrl, desc, tok, wsc, out);
}